// Round 1
// baseline (7831.119 us; speedup 1.0000x reference)
//
#include <hip/hip_runtime.h>
#include <hip/hip_bf16.h>

// ---------------------------------------------------------------------------
// JKNet: 3x (bipartite SAGEConv(mean) + BN(eval) + ReLU) -> JK concat -> linear
//        -> log_softmax
// Sizes: L0: 200000->100000 (K=128), L1: 100000->50000 (K=256),
//        L2: 50000->25000 (K=256). E = {1.6M, 0.8M, 0.4M}. OUT = 25000 x 47.
// ---------------------------------------------------------------------------

#define N_DST0 100000
#define N_DST1 50000
#define N_DST2 25000
#define HID 256
#define OUTC 47
#define ENDR 25000
#define BN_SCALE 0.99999500003749969f  // rsqrt(1 + 1e-5)

// ---------------------------------------------------------------------------
// Scatter-add (mean numerator + count). One thread per (edge, 4-channel quad).
// ---------------------------------------------------------------------------
template<int LOGK>
__global__ __launch_bounds__(256) void scatter4(
    const float* __restrict__ xsrc, const int* __restrict__ row,
    const int* __restrict__ col, float* __restrict__ agg,
    float* __restrict__ cnt, int E)
{
    const int QK = 1 << (LOGK - 2);  // float4 quads per edge
    long long gid = (long long)blockIdx.x * 256 + threadIdx.x;
    if (gid >= ((long long)E << (LOGK - 2))) return;
    int e = (int)(gid >> (LOGK - 2));
    int q = (int)(gid & (QK - 1));
    int r = row[e], d = col[e];
    const float4 v = *(const float4*)&xsrc[((size_t)r << LOGK) + q * 4];
    float* dst = &agg[((size_t)d << LOGK) + q * 4];
    atomicAdd(dst + 0, v.x);
    atomicAdd(dst + 1, v.y);
    atomicAdd(dst + 2, v.z);
    atomicAdd(dst + 3, v.w);
    if (q == 0) atomicAdd(&cnt[d], 1.0f);
}

// ---------------------------------------------------------------------------
// Fused dual GEMM + BN + ReLU:
//   h[m][n] = relu(( (agg[m]/max(cnt,1)) . Wl[n] + xdst[m] . Wr[n] )*s*g[n]+b[n])
// Treated as one GEMM with K' = 2K: A' = [agg/cnt | xdst], B' = [Wl | Wr].
// Block: 256 threads = 4 waves. Tile: 64 rows x 256 cols (all of N).
// Thread (tm=wave, tn=lane) computes 16 rows x 4 cols.
// ---------------------------------------------------------------------------
template<int K>
__global__ __launch_bounds__(256) void sage_gemm(
    const float* __restrict__ agg, const float* __restrict__ xdst,
    const float* __restrict__ cnt,
    const float* __restrict__ Wl, const float* __restrict__ Wr,
    const float* __restrict__ g, const float* __restrict__ b,
    float* __restrict__ h, int n_dst)
{
    __shared__ float A_lds[64][36];    // [m][k], stride 36 keeps writes ~2-way
    __shared__ float B_lds[32][256];   // [k][n]
    __shared__ float invc[64];

    const int tid = threadIdx.x;
    const int m0g = blockIdx.x * 64;
    const int tn = tid & 63;       // lane -> 4 output cols at tn*4
    const int tm = tid >> 6;       // wave -> 16 output rows at tm*16

    float acc[16][4] = {};

    if (tid < 64) {
        int r = m0g + tid;
        float c = (r < n_dst) ? cnt[r] : 1.0f;
        invc[tid] = 1.0f / fmaxf(c, 1.0f);
    }
    __syncthreads();

    for (int kp = 0; kp < 2 * K; kp += 32) {
        const bool left = kp < K;
        const float* Asrc = left ? agg : xdst;
        const float* Bsrc = left ? Wl : Wr;
        const int kbase = left ? kp : kp - K;

        // --- stage A tile: 64 rows x 32 k (each thread: 8 consecutive k) ---
        {
            int m = tid >> 2;
            int kc = (tid & 3) * 8;
            int r = m0g + m;
            float4 v0 = {0, 0, 0, 0}, v1 = {0, 0, 0, 0};
            if (r < n_dst) {
                const float* src = Asrc + (size_t)r * K + kbase + kc;
                v0 = *(const float4*)(src);
                v1 = *(const float4*)(src + 4);
                if (left) {
                    float ic = invc[m];
                    v0.x *= ic; v0.y *= ic; v0.z *= ic; v0.w *= ic;
                    v1.x *= ic; v1.y *= ic; v1.z *= ic; v1.w *= ic;
                }
            }
            *(float4*)&A_lds[m][kc] = v0;
            *(float4*)&A_lds[m][kc + 4] = v1;
        }
        // --- stage B tile: [k][n] = Bsrc[n][kbase+k], thread = n ---
        {
            const float* src = Bsrc + (size_t)tid * K + kbase;
#pragma unroll
            for (int k = 0; k < 32; k += 4) {
                float4 v = *(const float4*)(src + k);
                B_lds[k + 0][tid] = v.x;
                B_lds[k + 1][tid] = v.y;
                B_lds[k + 2][tid] = v.z;
                B_lds[k + 3][tid] = v.w;
            }
        }
        __syncthreads();

#pragma unroll 2
        for (int k = 0; k < 32; k += 4) {
            float4 b0 = *(const float4*)&B_lds[k + 0][tn * 4];
            float4 b1 = *(const float4*)&B_lds[k + 1][tn * 4];
            float4 b2 = *(const float4*)&B_lds[k + 2][tn * 4];
            float4 b3 = *(const float4*)&B_lds[k + 3][tn * 4];
#pragma unroll
            for (int i = 0; i < 16; ++i) {
                float4 a = *(const float4*)&A_lds[tm * 16 + i][k];
                acc[i][0] += a.x * b0.x + a.y * b1.x + a.z * b2.x + a.w * b3.x;
                acc[i][1] += a.x * b0.y + a.y * b1.y + a.z * b2.y + a.w * b3.y;
                acc[i][2] += a.x * b0.z + a.y * b1.z + a.z * b2.z + a.w * b3.z;
                acc[i][3] += a.x * b0.w + a.y * b1.w + a.z * b2.w + a.w * b3.w;
            }
        }
        __syncthreads();
    }

    // --- epilogue: BN (eval, mean=0/var=1 folded) + ReLU, coalesced store ---
    float4 gv = *(const float4*)&g[tn * 4];
    float4 bv = *(const float4*)&b[tn * 4];
#pragma unroll
    for (int i = 0; i < 16; ++i) {
        int r = m0g + tm * 16 + i;
        if (r < n_dst) {
            float4 o;
            o.x = fmaxf(acc[i][0] * BN_SCALE * gv.x + bv.x, 0.f);
            o.y = fmaxf(acc[i][1] * BN_SCALE * gv.y + bv.y, 0.f);
            o.z = fmaxf(acc[i][2] * BN_SCALE * gv.z + bv.z, 0.f);
            o.w = fmaxf(acc[i][3] * BN_SCALE * gv.w + bv.w, 0.f);
            *(float4*)&h[(size_t)r * HID + tn * 4] = o;
        }
    }
}

// ---------------------------------------------------------------------------
// Final: z = [h0|h1|h2][:25000] @ Wlin.T + blin ; out = log_softmax(z)
// Block: 256 threads = 4 waves, one row per wave; lane = class (47 of 64).
// Wlin staged through LDS in 256-wide chunks (shared by the 4 waves).
// ---------------------------------------------------------------------------
__global__ __launch_bounds__(256) void final_kernel(
    const float* __restrict__ h0, const float* __restrict__ h1,
    const float* __restrict__ h2, const float* __restrict__ Wlin,
    const float* __restrict__ blin, float* __restrict__ out)
{
    __shared__ float xrow[4][768];
    __shared__ float Wch[OUTC][260];   // stride 260: 16B-aligned, spread banks

    const int tid = threadIdx.x;
    const int wave = tid >> 6, lane = tid & 63;
    const int r0 = blockIdx.x * 4;

    // stage 4 rows of the concat [h0|h1|h2]
    for (int idx = tid; idx < 4 * 768; idx += 256) {
        int rr = idx / 768, j = idx % 768;
        size_t r = (size_t)(r0 + rr);
        float v;
        if (j < 256)       v = h0[r * HID + j];
        else if (j < 512)  v = h1[r * HID + (j - 256)];
        else               v = h2[r * HID + (j - 512)];
        xrow[rr][j] = v;
    }

    float acc = 0.f;
    for (int c0 = 0; c0 < 768; c0 += 256) {
        __syncthreads();
        for (int idx = tid; idx < OUTC * 256; idx += 256) {
            int n = idx >> 8, j = idx & 255;
            Wch[n][j] = Wlin[(size_t)n * 768 + c0 + j];
        }
        __syncthreads();
        if (lane < OUTC) {
            const float* wp = &Wch[lane][0];
            const float* xp = &xrow[wave][c0];
#pragma unroll 8
            for (int j = 0; j < 256; j += 4) {
                float4 wv = *(const float4*)(wp + j);
                float4 xv = *(const float4*)(xp + j);
                acc += wv.x * xv.x + wv.y * xv.y + wv.z * xv.z + wv.w * xv.w;
            }
        }
    }

    float z = (lane < OUTC) ? acc + blin[lane] : -INFINITY;
    float m = z;
#pragma unroll
    for (int off = 32; off >= 1; off >>= 1) m = fmaxf(m, __shfl_xor(m, off));
    float e = (lane < OUTC) ? expf(z - m) : 0.f;
    float s = e;
#pragma unroll
    for (int off = 32; off >= 1; off >>= 1) s += __shfl_xor(s, off);
    if (lane < OUTC) out[(size_t)(r0 + wave) * OUTC + lane] = z - m - logf(s);
}

// ---------------------------------------------------------------------------
extern "C" void kernel_launch(void* const* d_in, const int* in_sizes, int n_in,
                              void* d_out, int out_size, void* d_ws, size_t ws_size,
                              hipStream_t stream)
{
    const float* x    = (const float*)d_in[0];
    const int*   row0 = (const int*)d_in[1];
    const int*   col0 = (const int*)d_in[2];
    const int*   row1 = (const int*)d_in[3];
    const int*   col1 = (const int*)d_in[4];
    const int*   row2 = (const int*)d_in[5];
    const int*   col2 = (const int*)d_in[6];
    const float* Wl0  = (const float*)d_in[7];
    const float* Wr0  = (const float*)d_in[8];
    const float* g0   = (const float*)d_in[9];
    const float* b0   = (const float*)d_in[10];
    const float* Wl1  = (const float*)d_in[11];
    const float* Wr1  = (const float*)d_in[12];
    const float* g1   = (const float*)d_in[13];
    const float* b1   = (const float*)d_in[14];
    const float* Wl2  = (const float*)d_in[15];
    const float* Wr2  = (const float*)d_in[16];
    const float* g2   = (const float*)d_in[17];
    const float* b2   = (const float*)d_in[18];
    const float* Wlin = (const float*)d_in[19];
    const float* blin = (const float*)d_in[20];
    float* out = (float*)d_out;

    const int E0 = in_sizes[1], E1 = in_sizes[3], E2 = in_sizes[5];

    // workspace layout (floats): h0 | h1 | h2 | agg | cnt   (~231 MB total)
    float* ws  = (float*)d_ws;
    float* h0  = ws;                                  // 100000*256
    float* h1  = h0 + (size_t)N_DST0 * HID;           // 50000*256
    float* h2  = h1 + (size_t)N_DST1 * HID;           // 25000*256
    float* agg = h2 + (size_t)N_DST2 * HID;           // max 100000*128 = 12.8M
    float* cnt = agg + (size_t)12800000;              // 100000

    // ---------------- layer 0: K=128, 200000 -> 100000 ----------------
    hipMemsetAsync(agg, 0, (size_t)N_DST0 * 128 * sizeof(float), stream);
    hipMemsetAsync(cnt, 0, (size_t)N_DST0 * sizeof(float), stream);
    {
        long long tot = (long long)E0 << (7 - 2);
        int blocks = (int)((tot + 255) / 256);
        scatter4<7><<<blocks, 256, 0, stream>>>(x, row0, col0, agg, cnt, E0);
        sage_gemm<128><<<(N_DST0 + 63) / 64, 256, 0, stream>>>(
            agg, x, cnt, Wl0, Wr0, g0, b0, h0, N_DST0);
    }
    // ---------------- layer 1: K=256, 100000 -> 50000 ----------------
    hipMemsetAsync(agg, 0, (size_t)N_DST1 * HID * sizeof(float), stream);
    hipMemsetAsync(cnt, 0, (size_t)N_DST1 * sizeof(float), stream);
    {
        long long tot = (long long)E1 << (8 - 2);
        int blocks = (int)((tot + 255) / 256);
        scatter4<8><<<blocks, 256, 0, stream>>>(h0, row1, col1, agg, cnt, E1);
        sage_gemm<256><<<(N_DST1 + 63) / 64, 256, 0, stream>>>(
            agg, h0, cnt, Wl1, Wr1, g1, b1, h1, N_DST1);
    }
    // ---------------- layer 2: K=256, 50000 -> 25000 ----------------
    hipMemsetAsync(agg, 0, (size_t)N_DST2 * HID * sizeof(float), stream);
    hipMemsetAsync(cnt, 0, (size_t)N_DST2 * sizeof(float), stream);
    {
        long long tot = (long long)E2 << (8 - 2);
        int blocks = (int)((tot + 255) / 256);
        scatter4<8><<<blocks, 256, 0, stream>>>(h1, row2, col2, agg, cnt, E2);
        sage_gemm<256><<<(N_DST2 + 63) / 64, 256, 0, stream>>>(
            agg, h1, cnt, Wl2, Wr2, g2, b2, h2, N_DST2);
    }
    // ---------------- JK concat + linear + log_softmax ----------------
    final_kernel<<<ENDR / 4, 256, 0, stream>>>(h0, h1, h2, Wlin, blin, out);
}

// Round 2
// 1569.790 us; speedup vs baseline: 4.9886x; 4.9886x over previous
//
#include <hip/hip_runtime.h>
#include <hip/hip_bf16.h>

// ---------------------------------------------------------------------------
// JKNet: 3x (bipartite SAGEConv(mean) + BN(eval) + ReLU) -> JK concat -> linear
//        -> log_softmax
// Aggregation via on-device CSR build + wave-per-dst gather (no float atomics).
// ---------------------------------------------------------------------------

#define N_DST0 100000
#define N_DST1 50000
#define N_DST2 25000
#define HID 256
#define OUTC 47
#define ENDR 25000
#define BN_SCALE 0.99999500003749969f  // rsqrt(1 + 1e-5)

// ---------------------------------------------------------------------------
// CSR build: degree histogram
// ---------------------------------------------------------------------------
__global__ __launch_bounds__(256) void deg_count(
    const int* __restrict__ col, int* __restrict__ deg, int E)
{
    int e = blockIdx.x * 256 + threadIdx.x;
    if (e < E) atomicAdd(&deg[col[e]], 1);
}

// Two-level exclusive scan: block-local (1024 elems / block, 256 thr x 4)
__global__ __launch_bounds__(256) void scan_local(
    const int* __restrict__ deg, int* __restrict__ excl,
    int* __restrict__ blksum, int n)
{
    __shared__ int tsum[256];
    const int t = threadIdx.x;
    const int base = blockIdx.x * 1024 + t * 4;
    int v[4], s = 0;
#pragma unroll
    for (int j = 0; j < 4; ++j) {
        int idx = base + j;
        v[j] = (idx < n) ? deg[idx] : 0;
        s += v[j];
    }
    tsum[t] = s;
    __syncthreads();
    for (int off = 1; off < 256; off <<= 1) {
        int x = (t >= off) ? tsum[t - off] : 0;
        __syncthreads();
        tsum[t] += x;
        __syncthreads();
    }
    if (t == 255) blksum[blockIdx.x] = tsum[255];
    int run = tsum[t] - s;  // exclusive prefix of this thread within block
#pragma unroll
    for (int j = 0; j < 4; ++j) {
        int idx = base + j;
        if (idx < n) excl[idx] = run;
        run += v[j];
    }
}

__global__ __launch_bounds__(256) void scan_blksum(int* __restrict__ blksum, int nb)
{
    __shared__ int sh[256];
    const int t = threadIdx.x;
    int v = (t < nb) ? blksum[t] : 0;
    sh[t] = v;
    __syncthreads();
    for (int off = 1; off < 256; off <<= 1) {
        int x = (t >= off) ? sh[t - off] : 0;
        __syncthreads();
        sh[t] += x;
        __syncthreads();
    }
    if (t < nb) blksum[t] = sh[t] - v;  // exclusive
}

__global__ __launch_bounds__(256) void add_offsets(
    int* __restrict__ excl, const int* __restrict__ blkoff,
    int* __restrict__ cursor, int n)
{
    int i = blockIdx.x * 256 + threadIdx.x;
    if (i < n) {
        int v = excl[i] + blkoff[i >> 10];
        excl[i] = v;
        cursor[i] = v;
    }
}

__global__ __launch_bounds__(256) void csr_fill(
    const int* __restrict__ row, const int* __restrict__ col,
    int* __restrict__ cursor, int* __restrict__ esrc, int E)
{
    int e = blockIdx.x * 256 + threadIdx.x;
    if (e < E) {
        int pos = atomicAdd(&cursor[col[e]], 1);
        esrc[pos] = row[e];
    }
}

// ---------------------------------------------------------------------------
// Gather-mean: one wave per destination node. Lanes own channels
// (float2 for K=128, float4 for K=256); each edge's source row is read as one
// coalesced 512B/1KB wave transaction (L3-resident).
// ---------------------------------------------------------------------------
template<int LOGK>
__global__ __launch_bounds__(256) void gather_mean(
    const float* __restrict__ xsrc, const int* __restrict__ esrc,
    const int* __restrict__ start, const int* __restrict__ deg,
    float* __restrict__ agg, int n_dst)
{
    const int wid = (blockIdx.x * 256 + threadIdx.x) >> 6;
    const int lane = threadIdx.x & 63;
    if (wid >= n_dst) return;
    const int s = start[wid];
    const int d = deg[wid];
    const float inv = 1.0f / (float)max(d, 1);

    if (LOGK == 7) {
        float2 acc = {0.f, 0.f};
        int r_next = (d > 0) ? esrc[s] : 0;
        for (int i = 0; i < d; ++i) {
            int r = r_next;
            if (i + 1 < d) r_next = esrc[s + i + 1];
            float2 v = *(const float2*)&xsrc[((size_t)r << 7) + lane * 2];
            acc.x += v.x; acc.y += v.y;
        }
        acc.x *= inv; acc.y *= inv;
        *(float2*)&agg[((size_t)wid << 7) + lane * 2] = acc;
    } else {
        float4 acc = {0.f, 0.f, 0.f, 0.f};
        int r_next = (d > 0) ? esrc[s] : 0;
        for (int i = 0; i < d; ++i) {
            int r = r_next;
            if (i + 1 < d) r_next = esrc[s + i + 1];
            float4 v = *(const float4*)&xsrc[((size_t)r << 8) + lane * 4];
            acc.x += v.x; acc.y += v.y; acc.z += v.z; acc.w += v.w;
        }
        acc.x *= inv; acc.y *= inv; acc.z *= inv; acc.w *= inv;
        *(float4*)&agg[((size_t)wid << 8) + lane * 4] = acc;
    }
}

// ---------------------------------------------------------------------------
// Fused dual GEMM + BN + ReLU (agg already holds the mean):
//   h[m][n] = relu((agg[m].Wl[n] + xdst[m].Wr[n]) * s * g[n] + b[n])
// One GEMM with K' = 2K: A' = [agg | xdst], B' = [Wl | Wr].
// Block: 256 threads = 4 waves. Tile: 64 rows x 256 cols (all of N).
// ---------------------------------------------------------------------------
template<int K>
__global__ __launch_bounds__(256) void sage_gemm(
    const float* __restrict__ agg, const float* __restrict__ xdst,
    const float* __restrict__ Wl, const float* __restrict__ Wr,
    const float* __restrict__ g, const float* __restrict__ b,
    float* __restrict__ h, int n_dst)
{
    __shared__ float A_lds[64][36];
    __shared__ float B_lds[32][256];

    const int tid = threadIdx.x;
    const int m0g = blockIdx.x * 64;
    const int tn = tid & 63;
    const int tm = tid >> 6;

    float acc[16][4] = {};

    for (int kp = 0; kp < 2 * K; kp += 32) {
        const bool left = kp < K;
        const float* Asrc = left ? agg : xdst;
        const float* Bsrc = left ? Wl : Wr;
        const int kbase = left ? kp : kp - K;

        {
            int m = tid >> 2;
            int kc = (tid & 3) * 8;
            int r = m0g + m;
            float4 v0 = {0, 0, 0, 0}, v1 = {0, 0, 0, 0};
            if (r < n_dst) {
                const float* src = Asrc + (size_t)r * K + kbase + kc;
                v0 = *(const float4*)(src);
                v1 = *(const float4*)(src + 4);
            }
            *(float4*)&A_lds[m][kc] = v0;
            *(float4*)&A_lds[m][kc + 4] = v1;
        }
        {
            const float* src = Bsrc + (size_t)tid * K + kbase;
#pragma unroll
            for (int k = 0; k < 32; k += 4) {
                float4 v = *(const float4*)(src + k);
                B_lds[k + 0][tid] = v.x;
                B_lds[k + 1][tid] = v.y;
                B_lds[k + 2][tid] = v.z;
                B_lds[k + 3][tid] = v.w;
            }
        }
        __syncthreads();

#pragma unroll 2
        for (int k = 0; k < 32; k += 4) {
            float4 b0 = *(const float4*)&B_lds[k + 0][tn * 4];
            float4 b1 = *(const float4*)&B_lds[k + 1][tn * 4];
            float4 b2 = *(const float4*)&B_lds[k + 2][tn * 4];
            float4 b3 = *(const float4*)&B_lds[k + 3][tn * 4];
#pragma unroll
            for (int i = 0; i < 16; ++i) {
                float4 a = *(const float4*)&A_lds[tm * 16 + i][k];
                acc[i][0] += a.x * b0.x + a.y * b1.x + a.z * b2.x + a.w * b3.x;
                acc[i][1] += a.x * b0.y + a.y * b1.y + a.z * b2.y + a.w * b3.y;
                acc[i][2] += a.x * b0.z + a.y * b1.z + a.z * b2.z + a.w * b3.z;
                acc[i][3] += a.x * b0.w + a.y * b1.w + a.z * b2.w + a.w * b3.w;
            }
        }
        __syncthreads();
    }

    float4 gv = *(const float4*)&g[tn * 4];
    float4 bv = *(const float4*)&b[tn * 4];
#pragma unroll
    for (int i = 0; i < 16; ++i) {
        int r = m0g + tm * 16 + i;
        if (r < n_dst) {
            float4 o;
            o.x = fmaxf(acc[i][0] * BN_SCALE * gv.x + bv.x, 0.f);
            o.y = fmaxf(acc[i][1] * BN_SCALE * gv.y + bv.y, 0.f);
            o.z = fmaxf(acc[i][2] * BN_SCALE * gv.z + bv.z, 0.f);
            o.w = fmaxf(acc[i][3] * BN_SCALE * gv.w + bv.w, 0.f);
            *(float4*)&h[(size_t)r * HID + tn * 4] = o;
        }
    }
}

// ---------------------------------------------------------------------------
// Final: z = [h0|h1|h2][:25000] @ Wlin.T + blin ; out = log_softmax(z)
// ---------------------------------------------------------------------------
__global__ __launch_bounds__(256) void final_kernel(
    const float* __restrict__ h0, const float* __restrict__ h1,
    const float* __restrict__ h2, const float* __restrict__ Wlin,
    const float* __restrict__ blin, float* __restrict__ out)
{
    __shared__ float xrow[4][768];
    __shared__ float Wch[OUTC][260];

    const int tid = threadIdx.x;
    const int wave = tid >> 6, lane = tid & 63;
    const int r0 = blockIdx.x * 4;

    for (int idx = tid; idx < 4 * 768; idx += 256) {
        int rr = idx / 768, j = idx % 768;
        size_t r = (size_t)(r0 + rr);
        float v;
        if (j < 256)       v = h0[r * HID + j];
        else if (j < 512)  v = h1[r * HID + (j - 256)];
        else               v = h2[r * HID + (j - 512)];
        xrow[rr][j] = v;
    }

    float acc = 0.f;
    for (int c0 = 0; c0 < 768; c0 += 256) {
        __syncthreads();
        for (int idx = tid; idx < OUTC * 256; idx += 256) {
            int n = idx >> 8, j = idx & 255;
            Wch[n][j] = Wlin[(size_t)n * 768 + c0 + j];
        }
        __syncthreads();
        if (lane < OUTC) {
            const float* wp = &Wch[lane][0];
            const float* xp = &xrow[wave][c0];
#pragma unroll 8
            for (int j = 0; j < 256; j += 4) {
                float4 wv = *(const float4*)(wp + j);
                float4 xv = *(const float4*)(xp + j);
                acc += wv.x * xv.x + wv.y * xv.y + wv.z * xv.z + wv.w * xv.w;
            }
        }
    }

    float z = (lane < OUTC) ? acc + blin[lane] : -INFINITY;
    float m = z;
#pragma unroll
    for (int off = 32; off >= 1; off >>= 1) m = fmaxf(m, __shfl_xor(m, off));
    float e = (lane < OUTC) ? expf(z - m) : 0.f;
    float s = e;
#pragma unroll
    for (int off = 32; off >= 1; off >>= 1) s += __shfl_xor(s, off);
    if (lane < OUTC) out[(size_t)(r0 + wave) * OUTC + lane] = z - m - logf(s);
}

// ---------------------------------------------------------------------------
extern "C" void kernel_launch(void* const* d_in, const int* in_sizes, int n_in,
                              void* d_out, int out_size, void* d_ws, size_t ws_size,
                              hipStream_t stream)
{
    const float* x    = (const float*)d_in[0];
    const int* rows[3] = {(const int*)d_in[1], (const int*)d_in[3], (const int*)d_in[5]};
    const int* cols[3] = {(const int*)d_in[2], (const int*)d_in[4], (const int*)d_in[6]};
    const float* Wl[3] = {(const float*)d_in[7],  (const float*)d_in[11], (const float*)d_in[15]};
    const float* Wr[3] = {(const float*)d_in[8],  (const float*)d_in[12], (const float*)d_in[16]};
    const float* gs[3] = {(const float*)d_in[9],  (const float*)d_in[13], (const float*)d_in[17]};
    const float* bs[3] = {(const float*)d_in[10], (const float*)d_in[14], (const float*)d_in[18]};
    const float* Wlin = (const float*)d_in[19];
    const float* blin = (const float*)d_in[20];
    float* out = (float*)d_out;

    const int Es[3]    = {in_sizes[1], in_sizes[3], in_sizes[5]};
    const int ndst[3]  = {N_DST0, N_DST1, N_DST2};

    // workspace layout (floats): h0 | h1 | h2 | agg
    // CSR int scratch aliased into the h2 region (h2 is only written by the
    // layer-2 GEMM, strictly after the layer-2 CSR is consumed).
    float* ws  = (float*)d_ws;
    float* h0  = ws;
    float* h1  = h0 + (size_t)N_DST0 * HID;
    float* h2  = h1 + (size_t)N_DST1 * HID;
    float* agg = h2 + (size_t)N_DST2 * HID;

    int* ibase  = (int*)h2;          // 6.4M ints capacity
    int* esrc   = ibase;             // up to 1.6M
    int* deg    = ibase + 1600000;   // up to 100k
    int* excl   = ibase + 1700000;   // up to 100k
    int* cursor = ibase + 1800000;   // up to 100k
    int* blkoff = ibase + 1900000;   // up to 128

    const float* hsrc[3] = {x, h0, h1};
    float* hdst[3] = {h0, h1, h2};

    for (int L = 0; L < 3; ++L) {
        const int E = Es[L], nd = ndst[L];
        const int nb = (nd + 1023) / 1024;
        hipMemsetAsync(deg, 0, (size_t)nd * sizeof(int), stream);
        deg_count<<<(E + 255) / 256, 256, 0, stream>>>(cols[L], deg, E);
        scan_local<<<nb, 256, 0, stream>>>(deg, excl, blkoff, nd);
        scan_blksum<<<1, 256, 0, stream>>>(blkoff, nb);
        add_offsets<<<(nd + 255) / 256, 256, 0, stream>>>(excl, blkoff, cursor, nd);
        csr_fill<<<(E + 255) / 256, 256, 0, stream>>>(rows[L], cols[L], cursor, esrc, E);

        if (L == 0) {
            gather_mean<7><<<(nd + 3) / 4, 256, 0, stream>>>(hsrc[L], esrc, excl, deg, agg, nd);
            sage_gemm<128><<<(nd + 63) / 64, 256, 0, stream>>>(
                agg, hsrc[L], Wl[L], Wr[L], gs[L], bs[L], hdst[L], nd);
        } else {
            gather_mean<8><<<(nd + 3) / 4, 256, 0, stream>>>(hsrc[L], esrc, excl, deg, agg, nd);
            sage_gemm<256><<<(nd + 63) / 64, 256, 0, stream>>>(
                agg, hsrc[L], Wl[L], Wr[L], gs[L], bs[L], hdst[L], nd);
        }
    }

    final_kernel<<<ENDR / 4, 256, 0, stream>>>(h0, h1, h2, Wlin, blin, out);
}

// Round 4
// 867.556 us; speedup vs baseline: 9.0266x; 1.8094x over previous
//
#include <hip/hip_runtime.h>
#include <hip/hip_bf16.h>

// ---------------------------------------------------------------------------
// JKNet: 3x (bipartite SAGEConv(mean) + BN(eval) + ReLU) -> JK concat -> linear
//        -> log_softmax
// CSR-build + bf16 gather + bf16 MFMA GEMM (fp32 accum) + fused BN/ReLU.
// R4 fix: CSR int scratch moved past the bf16 weight region (R3 overlapped
// esrc with Wrb[2] tail -> inf/NaN weights -> NaN output).
// ---------------------------------------------------------------------------

#define N_DST0 100000
#define N_DST1 50000
#define N_DST2 25000
#define HID 256
#define OUTC 47
#define ENDR 25000
#define BN_SCALE 0.99999500003749969f  // rsqrt(1 + 1e-5)

typedef __attribute__((ext_vector_type(8))) short short8;
typedef __attribute__((ext_vector_type(4))) float f32x4;

__device__ __forceinline__ unsigned short f2b1(float f) {
    unsigned int u = __float_as_uint(f);
    return (unsigned short)((u + 0x7fffu + ((u >> 16) & 1u)) >> 16);  // RNE
}
__device__ __forceinline__ float b2f_lo(unsigned int v) {
    return __uint_as_float(v << 16);
}
__device__ __forceinline__ float b2f_hi(unsigned int v) {
    return __uint_as_float(v & 0xffff0000u);
}

// ---------------------------------------------------------------------------
// fp32 -> bf16 conversion (n must be a multiple of 4)
// ---------------------------------------------------------------------------
__global__ __launch_bounds__(256) void f2b_kernel(
    const float* __restrict__ in, unsigned short* __restrict__ out, int n)
{
    int i = (blockIdx.x * 256 + threadIdx.x) * 4;
    if (i < n) {
        float4 v = *(const float4*)&in[i];
        uint2 o;
        o.x = (unsigned int)f2b1(v.x) | ((unsigned int)f2b1(v.y) << 16);
        o.y = (unsigned int)f2b1(v.z) | ((unsigned int)f2b1(v.w) << 16);
        *(uint2*)&out[i] = o;
    }
}

// ---------------------------------------------------------------------------
// CSR build
// ---------------------------------------------------------------------------
__global__ __launch_bounds__(256) void deg_count(
    const int* __restrict__ col, int* __restrict__ deg, int E)
{
    int e = blockIdx.x * 256 + threadIdx.x;
    if (e < E) atomicAdd(&deg[col[e]], 1);
}

__global__ __launch_bounds__(256) void scan_local(
    const int* __restrict__ deg, int* __restrict__ excl,
    int* __restrict__ blksum, int n)
{
    __shared__ int tsum[256];
    const int t = threadIdx.x;
    const int base = blockIdx.x * 1024 + t * 4;
    int v[4], s = 0;
#pragma unroll
    for (int j = 0; j < 4; ++j) {
        int idx = base + j;
        v[j] = (idx < n) ? deg[idx] : 0;
        s += v[j];
    }
    tsum[t] = s;
    __syncthreads();
    for (int off = 1; off < 256; off <<= 1) {
        int x = (t >= off) ? tsum[t - off] : 0;
        __syncthreads();
        tsum[t] += x;
        __syncthreads();
    }
    if (t == 255) blksum[blockIdx.x] = tsum[255];
    int run = tsum[t] - s;
#pragma unroll
    for (int j = 0; j < 4; ++j) {
        int idx = base + j;
        if (idx < n) excl[idx] = run;
        run += v[j];
    }
}

__global__ __launch_bounds__(256) void scan_blksum(int* __restrict__ blksum, int nb)
{
    __shared__ int sh[256];
    const int t = threadIdx.x;
    int v = (t < nb) ? blksum[t] : 0;
    sh[t] = v;
    __syncthreads();
    for (int off = 1; off < 256; off <<= 1) {
        int x = (t >= off) ? sh[t - off] : 0;
        __syncthreads();
        sh[t] += x;
        __syncthreads();
    }
    if (t < nb) blksum[t] = sh[t] - v;
}

__global__ __launch_bounds__(256) void add_offsets(
    int* __restrict__ excl, const int* __restrict__ blkoff,
    int* __restrict__ cursor, int n)
{
    int i = blockIdx.x * 256 + threadIdx.x;
    if (i < n) {
        int v = excl[i] + blkoff[i >> 10];
        excl[i] = v;
        cursor[i] = v;
    }
}

__global__ __launch_bounds__(256) void csr_fill(
    const int* __restrict__ row, const int* __restrict__ col,
    int* __restrict__ cursor, int* __restrict__ esrc, int E)
{
    int e = blockIdx.x * 256 + threadIdx.x;
    if (e < E) {
        int pos = atomicAdd(&cursor[col[e]], 1);
        esrc[pos] = row[e];
    }
}

// ---------------------------------------------------------------------------
// Gather-mean over bf16 sources -> bf16 agg. One wave per destination node.
// ---------------------------------------------------------------------------
template<int LOGK>
__global__ __launch_bounds__(256) void gather_mean(
    const unsigned short* __restrict__ xsrc, const int* __restrict__ esrc,
    const int* __restrict__ start, const int* __restrict__ deg,
    unsigned short* __restrict__ agg, int n_dst)
{
    const int wid = (blockIdx.x * 256 + threadIdx.x) >> 6;
    const int lane = threadIdx.x & 63;
    if (wid >= n_dst) return;
    const int s = start[wid];
    const int d = deg[wid];
    const float inv = 1.0f / (float)max(d, 1);

    if (LOGK == 7) {
        float ax = 0.f, ay = 0.f;
        int i = 0;
        for (; i + 2 <= d; i += 2) {
            int r0 = esrc[s + i], r1 = esrc[s + i + 1];
            unsigned int v0 = *(const unsigned int*)&xsrc[((size_t)r0 << 7) + lane * 2];
            unsigned int v1 = *(const unsigned int*)&xsrc[((size_t)r1 << 7) + lane * 2];
            ax += b2f_lo(v0); ay += b2f_hi(v0);
            ax += b2f_lo(v1); ay += b2f_hi(v1);
        }
        if (i < d) {
            int r0 = esrc[s + i];
            unsigned int v0 = *(const unsigned int*)&xsrc[((size_t)r0 << 7) + lane * 2];
            ax += b2f_lo(v0); ay += b2f_hi(v0);
        }
        ax *= inv; ay *= inv;
        *(unsigned int*)&agg[((size_t)wid << 7) + lane * 2] =
            (unsigned int)f2b1(ax) | ((unsigned int)f2b1(ay) << 16);
    } else {
        float ax = 0.f, ay = 0.f, az = 0.f, aw = 0.f;
        int i = 0;
        for (; i + 2 <= d; i += 2) {
            int r0 = esrc[s + i], r1 = esrc[s + i + 1];
            uint2 v0 = *(const uint2*)&xsrc[((size_t)r0 << 8) + lane * 4];
            uint2 v1 = *(const uint2*)&xsrc[((size_t)r1 << 8) + lane * 4];
            ax += b2f_lo(v0.x); ay += b2f_hi(v0.x);
            az += b2f_lo(v0.y); aw += b2f_hi(v0.y);
            ax += b2f_lo(v1.x); ay += b2f_hi(v1.x);
            az += b2f_lo(v1.y); aw += b2f_hi(v1.y);
        }
        if (i < d) {
            int r0 = esrc[s + i];
            uint2 v0 = *(const uint2*)&xsrc[((size_t)r0 << 8) + lane * 4];
            ax += b2f_lo(v0.x); ay += b2f_hi(v0.x);
            az += b2f_lo(v0.y); aw += b2f_hi(v0.y);
        }
        ax *= inv; ay *= inv; az *= inv; aw *= inv;
        uint2 o;
        o.x = (unsigned int)f2b1(ax) | ((unsigned int)f2b1(ay) << 16);
        o.y = (unsigned int)f2b1(az) | ((unsigned int)f2b1(aw) << 16);
        *(uint2*)&agg[((size_t)wid << 8) + lane * 4] = o;
    }
}

// ---------------------------------------------------------------------------
// bf16 MFMA GEMM: h = relu((agg.Wl^T + xdst.Wr^T) * BN_SCALE * g + b), bf16 out
// Block: 512 threads = 8 waves (2 M-halves x 4 N-quarters). Tile 128 x 256.
// mfma_f32_16x16x32_bf16; LDS 16B-groups XOR-swizzled (g ^= (row>>1)&3).
// ---------------------------------------------------------------------------
template<int KH>
__global__ __launch_bounds__(512) void sage_gemm_mfma(
    const unsigned short* __restrict__ aggb, const unsigned short* __restrict__ xdstb,
    const unsigned short* __restrict__ Wlb, const unsigned short* __restrict__ Wrb,
    const float* __restrict__ g, const float* __restrict__ b,
    unsigned short* __restrict__ h, int n_dst)
{
    __shared__ uint4 A_sh[512];    // [m:128][g':4]
    __shared__ uint4 B_sh[1024];   // [n:256][g':4]

    const int tid  = threadIdx.x;
    const int lane = tid & 63;
    const int wv   = tid >> 6;
    const int mh   = wv >> 2;
    const int n0   = (wv & 3) * 64;
    const int m0g  = blockIdx.x * 128;
    const int lrow = lane & 15;
    const int lgrp = lane >> 4;

    f32x4 acc[4][4];
#pragma unroll
    for (int i = 0; i < 4; ++i)
#pragma unroll
        for (int j = 0; j < 4; ++j)
            acc[i][j] = (f32x4){0.f, 0.f, 0.f, 0.f};

    for (int kp = 0; kp < 2 * KH; kp += 32) {
        const unsigned short* Asrc = (kp < KH) ? aggb : xdstb;
        const unsigned short* Bsrc = (kp < KH) ? Wlb : Wrb;
        const int kbase = (kp < KH) ? kp : kp - KH;

        // stage A: 128 rows x 32 k (1 x 16B per thread)
        {
            int m = tid >> 2, gq = tid & 3;
            int r = m0g + m;
            uint4 v = {0, 0, 0, 0};
            if (r < n_dst) v = *(const uint4*)&Asrc[(size_t)r * KH + kbase + gq * 8];
            A_sh[m * 4 + (gq ^ ((m >> 1) & 3))] = v;
        }
        // stage B: 256 rows x 32 k (2 x 16B per thread)
        {
            int nb_ = tid >> 2, gq = tid & 3;
#pragma unroll
            for (int i2 = 0; i2 < 2; ++i2) {
                int n = nb_ + 128 * i2;
                uint4 v = *(const uint4*)&Bsrc[(size_t)n * KH + kbase + gq * 8];
                B_sh[n * 4 + (gq ^ ((n >> 1) & 3))] = v;
            }
        }
        __syncthreads();

        short8 av[4], bv[4];
#pragma unroll
        for (int mf = 0; mf < 4; ++mf) {
            int m = mh * 64 + mf * 16 + lrow;
            av[mf] = *reinterpret_cast<const short8*>(&A_sh[m * 4 + (lgrp ^ ((m >> 1) & 3))]);
        }
#pragma unroll
        for (int nf = 0; nf < 4; ++nf) {
            int n = n0 + nf * 16 + lrow;
            bv[nf] = *reinterpret_cast<const short8*>(&B_sh[n * 4 + (lgrp ^ ((n >> 1) & 3))]);
        }
#pragma unroll
        for (int mf = 0; mf < 4; ++mf)
#pragma unroll
            for (int nf = 0; nf < 4; ++nf)
                acc[mf][nf] = __builtin_amdgcn_mfma_f32_16x16x32_bf16(
                    av[mf], bv[nf], acc[mf][nf], 0, 0, 0);
        __syncthreads();
    }

    // epilogue: BN + ReLU, bf16 store. C/D: col=lane&15, row=(lane>>4)*4+reg.
#pragma unroll
    for (int nf = 0; nf < 4; ++nf) {
        int n = n0 + nf * 16 + lrow;
        float sc = g[n] * BN_SCALE;
        float bi = b[n];
#pragma unroll
        for (int mf = 0; mf < 4; ++mf) {
            int mbase = m0g + mh * 64 + mf * 16 + lgrp * 4;
#pragma unroll
            for (int r = 0; r < 4; ++r) {
                int m = mbase + r;
                if (m < n_dst) {
                    float vv = fmaxf(acc[mf][nf][r] * sc + bi, 0.f);
                    h[(size_t)m * HID + n] = f2b1(vv);
                }
            }
        }
    }
}

// ---------------------------------------------------------------------------
// Final: z = [h0|h1|h2][:25000] @ Wlin.T + blin ; out = log_softmax(z)
// ---------------------------------------------------------------------------
__global__ __launch_bounds__(256) void final_kernel(
    const unsigned short* __restrict__ h0, const unsigned short* __restrict__ h1,
    const unsigned short* __restrict__ h2, const float* __restrict__ Wlin,
    const float* __restrict__ blin, float* __restrict__ out)
{
    __shared__ float xrow[4][768];
    __shared__ float Wch[OUTC][260];

    const int tid = threadIdx.x;
    const int wave = tid >> 6, lane = tid & 63;
    const int r0 = blockIdx.x * 4;

    for (int idx = tid; idx < 4 * 192; idx += 256) {
        int rr = idx / 192, j = (idx % 192) * 4;
        size_t r = (size_t)(r0 + rr);
        const unsigned short* src;
        if (j < 256)      src = &h0[r * HID + j];
        else if (j < 512) src = &h1[r * HID + (j - 256)];
        else              src = &h2[r * HID + (j - 512)];
        uint2 v = *(const uint2*)src;
        xrow[rr][j + 0] = b2f_lo(v.x);
        xrow[rr][j + 1] = b2f_hi(v.x);
        xrow[rr][j + 2] = b2f_lo(v.y);
        xrow[rr][j + 3] = b2f_hi(v.y);
    }

    float acc = 0.f;
    for (int c0 = 0; c0 < 768; c0 += 256) {
        __syncthreads();
        for (int idx = tid; idx < OUTC * 256; idx += 256) {
            int n = idx >> 8, j = idx & 255;
            Wch[n][j] = Wlin[(size_t)n * 768 + c0 + j];
        }
        __syncthreads();
        if (lane < OUTC) {
            const float* wp = &Wch[lane][0];
            const float* xp = &xrow[wave][c0];
#pragma unroll 8
            for (int j = 0; j < 256; j += 4) {
                float4 wv = *(const float4*)(wp + j);
                float4 xv = *(const float4*)(xp + j);
                acc += wv.x * xv.x + wv.y * xv.y + wv.z * xv.z + wv.w * xv.w;
            }
        }
    }

    float z = (lane < OUTC) ? acc + blin[lane] : -INFINITY;
    float m = z;
#pragma unroll
    for (int off = 32; off >= 1; off >>= 1) m = fmaxf(m, __shfl_xor(m, off));
    float e = (lane < OUTC) ? expf(z - m) : 0.f;
    float s = e;
#pragma unroll
    for (int off = 32; off >= 1; off >>= 1) s += __shfl_xor(s, off);
    if (lane < OUTC) out[(size_t)(r0 + wave) * OUTC + lane] = z - m - logf(s);
}

// ---------------------------------------------------------------------------
extern "C" void kernel_launch(void* const* d_in, const int* in_sizes, int n_in,
                              void* d_out, int out_size, void* d_ws, size_t ws_size,
                              hipStream_t stream)
{
    const float* x    = (const float*)d_in[0];
    const int* rows[3] = {(const int*)d_in[1], (const int*)d_in[3], (const int*)d_in[5]};
    const int* cols[3] = {(const int*)d_in[2], (const int*)d_in[4], (const int*)d_in[6]};
    const float* Wl[3] = {(const float*)d_in[7],  (const float*)d_in[11], (const float*)d_in[15]};
    const float* Wr[3] = {(const float*)d_in[8],  (const float*)d_in[12], (const float*)d_in[16]};
    const float* gs[3] = {(const float*)d_in[9],  (const float*)d_in[13], (const float*)d_in[17]};
    const float* bs[3] = {(const float*)d_in[10], (const float*)d_in[14], (const float*)d_in[18]};
    const float* Wlin = (const float*)d_in[19];
    const float* blin = (const float*)d_in[20];
    float* out = (float*)d_out;

    const int Es[3]   = {in_sizes[1], in_sizes[3], in_sizes[5]};
    const int ndst[3] = {N_DST0, N_DST1, N_DST2};
    const int Ks[3]   = {128, 256, 256};

    // ----- workspace layout (bytes) -----
    // xb   @ 0          : 200000*128 bf16 = 51,200,000
    // h0b  @ 51200000   : 100000*256 bf16 = 51,200,000
    // h1b  @ 102400000  :  50000*256 bf16 = 25,600,000
    // h2b  @ 128000000  :  25000*256 bf16 = 12,800,000
    // aggb @ 140800000  : max 12.8M bf16  = 25,600,000   (ends 166,400,000)
    // wb   @ 166400000  : 327,680 bf16 weights = 655,360 (ends 167,055,360)
    // ints @ 167200000  : esrc 1.6M | deg/excl/cursor 100k | blkoff
    char* base = (char*)d_ws;
    unsigned short* xb  = (unsigned short*)(base);
    unsigned short* h0b = (unsigned short*)(base + 51200000);
    unsigned short* h1b = (unsigned short*)(base + 102400000);
    unsigned short* h2b = (unsigned short*)(base + 128000000);
    unsigned short* aggb= (unsigned short*)(base + 140800000);
    unsigned short* wb  = (unsigned short*)(base + 166400000);
    int* ibase  = (int*)(base + 167200000);   // clear of weight region (R4 fix)
    int* esrc   = ibase;
    int* deg    = ibase + 1600000;
    int* excl   = ibase + 1700000;
    int* cursor = ibase + 1800000;
    int* blkoff = ibase + 1900000;

    // bf16 weight regions (compact: 32768+32768+65536*4 = 327,680 elems)
    unsigned short* Wlb[3] = {wb,          wb + 65536,  wb + 196608};
    unsigned short* Wrb[3] = {wb + 32768,  wb + 131072, wb + 262144};
    const int wsz[3] = {256 * 128, 256 * 256, 256 * 256};

    // ----- convert x and weights to bf16 -----
    f2b_kernel<<<(25600000 / 4 + 255) / 256, 256, 0, stream>>>(x, xb, 25600000);
    for (int L = 0; L < 3; ++L) {
        f2b_kernel<<<(wsz[L] / 4 + 255) / 256, 256, 0, stream>>>(Wl[L], Wlb[L], wsz[L]);
        f2b_kernel<<<(wsz[L] / 4 + 255) / 256, 256, 0, stream>>>(Wr[L], Wrb[L], wsz[L]);
    }

    const unsigned short* hsrc[3] = {xb, h0b, h1b};
    unsigned short* hdst[3] = {h0b, h1b, h2b};

    for (int L = 0; L < 3; ++L) {
        const int E = Es[L], nd = ndst[L];
        const int nb = (nd + 1023) / 1024;
        hipMemsetAsync(deg, 0, (size_t)nd * sizeof(int), stream);
        deg_count<<<(E + 255) / 256, 256, 0, stream>>>(cols[L], deg, E);
        scan_local<<<nb, 256, 0, stream>>>(deg, excl, blkoff, nd);
        scan_blksum<<<1, 256, 0, stream>>>(blkoff, nb);
        add_offsets<<<(nd + 255) / 256, 256, 0, stream>>>(excl, blkoff, cursor, nd);
        csr_fill<<<(E + 255) / 256, 256, 0, stream>>>(rows[L], cols[L], cursor, esrc, E);

        if (Ks[L] == 128) {
            gather_mean<7><<<(nd + 3) / 4, 256, 0, stream>>>(hsrc[L], esrc, excl, deg, aggb, nd);
            sage_gemm_mfma<128><<<(nd + 127) / 128, 512, 0, stream>>>(
                aggb, hsrc[L], Wlb[L], Wrb[L], gs[L], bs[L], hdst[L], nd);
        } else {
            gather_mean<8><<<(nd + 3) / 4, 256, 0, stream>>>(hsrc[L], esrc, excl, deg, aggb, nd);
            sage_gemm_mfma<256><<<(nd + 127) / 128, 512, 0, stream>>>(
                aggb, hsrc[L], Wlb[L], Wrb[L], gs[L], bs[L], hdst[L], nd);
        }
    }

    final_kernel<<<ENDR / 4, 256, 0, stream>>>(h0b, h1b, h2b, Wlin, blin, out);
}

// Round 5
// 690.070 us; speedup vs baseline: 11.3483x; 1.2572x over previous
//
#include <hip/hip_runtime.h>
#include <hip/hip_bf16.h>

// ---------------------------------------------------------------------------
// JKNet: 3x (bipartite SAGEConv(mean) + BN(eval) + ReLU) -> JK concat -> linear
//        -> log_softmax
// CSR-build + bf16 gather (4x unrolled) + bf16 MFMA GEMMs (incl. final layer
// with fused log_softmax).
// ---------------------------------------------------------------------------

#define N_DST0 100000
#define N_DST1 50000
#define N_DST2 25000
#define HID 256
#define OUTC 47
#define ENDR 25000
#define BN_SCALE 0.99999500003749969f  // rsqrt(1 + 1e-5)

typedef __attribute__((ext_vector_type(8))) short short8;
typedef __attribute__((ext_vector_type(4))) float f32x4;

__device__ __forceinline__ unsigned short f2b1(float f) {
    unsigned int u = __float_as_uint(f);
    return (unsigned short)((u + 0x7fffu + ((u >> 16) & 1u)) >> 16);  // RNE
}
__device__ __forceinline__ float b2f_lo(unsigned int v) {
    return __uint_as_float(v << 16);
}
__device__ __forceinline__ float b2f_hi(unsigned int v) {
    return __uint_as_float(v & 0xffff0000u);
}

// ---------------------------------------------------------------------------
// fp32 -> bf16 conversion (n must be a multiple of 4)
// ---------------------------------------------------------------------------
__global__ __launch_bounds__(256) void f2b_kernel(
    const float* __restrict__ in, unsigned short* __restrict__ out, int n)
{
    int i = (blockIdx.x * 256 + threadIdx.x) * 4;
    if (i < n) {
        float4 v = *(const float4*)&in[i];
        uint2 o;
        o.x = (unsigned int)f2b1(v.x) | ((unsigned int)f2b1(v.y) << 16);
        o.y = (unsigned int)f2b1(v.z) | ((unsigned int)f2b1(v.w) << 16);
        *(uint2*)&out[i] = o;
    }
}

// ---------------------------------------------------------------------------
// CSR build
// ---------------------------------------------------------------------------
__global__ __launch_bounds__(256) void deg_count(
    const int* __restrict__ col, int* __restrict__ deg, int E)
{
    int e = blockIdx.x * 256 + threadIdx.x;
    if (e < E) atomicAdd(&deg[col[e]], 1);
}

__global__ __launch_bounds__(256) void scan_local(
    const int* __restrict__ deg, int* __restrict__ excl,
    int* __restrict__ blksum, int n)
{
    __shared__ int tsum[256];
    const int t = threadIdx.x;
    const int base = blockIdx.x * 1024 + t * 4;
    int v[4], s = 0;
#pragma unroll
    for (int j = 0; j < 4; ++j) {
        int idx = base + j;
        v[j] = (idx < n) ? deg[idx] : 0;
        s += v[j];
    }
    tsum[t] = s;
    __syncthreads();
    for (int off = 1; off < 256; off <<= 1) {
        int x = (t >= off) ? tsum[t - off] : 0;
        __syncthreads();
        tsum[t] += x;
        __syncthreads();
    }
    if (t == 255) blksum[blockIdx.x] = tsum[255];
    int run = tsum[t] - s;
#pragma unroll
    for (int j = 0; j < 4; ++j) {
        int idx = base + j;
        if (idx < n) excl[idx] = run;
        run += v[j];
    }
}

__global__ __launch_bounds__(256) void scan_blksum(int* __restrict__ blksum, int nb)
{
    __shared__ int sh[256];
    const int t = threadIdx.x;
    int v = (t < nb) ? blksum[t] : 0;
    sh[t] = v;
    __syncthreads();
    for (int off = 1; off < 256; off <<= 1) {
        int x = (t >= off) ? sh[t - off] : 0;
        __syncthreads();
        sh[t] += x;
        __syncthreads();
    }
    if (t < nb) blksum[t] = sh[t] - v;
}

__global__ __launch_bounds__(256) void add_offsets(
    int* __restrict__ excl, const int* __restrict__ blkoff,
    int* __restrict__ cursor, int n)
{
    int i = blockIdx.x * 256 + threadIdx.x;
    if (i < n) {
        int v = excl[i] + blkoff[i >> 10];
        excl[i] = v;
        cursor[i] = v;
    }
}

__global__ __launch_bounds__(256) void csr_fill(
    const int* __restrict__ row, const int* __restrict__ col,
    int* __restrict__ cursor, int* __restrict__ esrc, int E)
{
    int e = blockIdx.x * 256 + threadIdx.x;
    if (e < E) {
        int pos = atomicAdd(&cursor[col[e]], 1);
        esrc[pos] = row[e];
    }
}

// ---------------------------------------------------------------------------
// Gather-mean over bf16 sources -> bf16 agg. One wave per destination node.
// 4-edge unroll for memory-level parallelism.
// ---------------------------------------------------------------------------
template<int LOGK>
__global__ __launch_bounds__(256) void gather_mean(
    const unsigned short* __restrict__ xsrc, const int* __restrict__ esrc,
    const int* __restrict__ start, const int* __restrict__ deg,
    unsigned short* __restrict__ agg, int n_dst)
{
    const int wid = (blockIdx.x * 256 + threadIdx.x) >> 6;
    const int lane = threadIdx.x & 63;
    if (wid >= n_dst) return;
    const int s = start[wid];
    const int d = deg[wid];
    const float inv = 1.0f / (float)max(d, 1);

    if (LOGK == 7) {
        float ax = 0.f, ay = 0.f;
        int i = 0;
        for (; i + 4 <= d; i += 4) {
            int r0 = esrc[s + i + 0], r1 = esrc[s + i + 1];
            int r2 = esrc[s + i + 2], r3 = esrc[s + i + 3];
            unsigned int v0 = *(const unsigned int*)&xsrc[((size_t)r0 << 7) + lane * 2];
            unsigned int v1 = *(const unsigned int*)&xsrc[((size_t)r1 << 7) + lane * 2];
            unsigned int v2 = *(const unsigned int*)&xsrc[((size_t)r2 << 7) + lane * 2];
            unsigned int v3 = *(const unsigned int*)&xsrc[((size_t)r3 << 7) + lane * 2];
            ax += b2f_lo(v0); ay += b2f_hi(v0);
            ax += b2f_lo(v1); ay += b2f_hi(v1);
            ax += b2f_lo(v2); ay += b2f_hi(v2);
            ax += b2f_lo(v3); ay += b2f_hi(v3);
        }
        for (; i < d; ++i) {
            int r0 = esrc[s + i];
            unsigned int v0 = *(const unsigned int*)&xsrc[((size_t)r0 << 7) + lane * 2];
            ax += b2f_lo(v0); ay += b2f_hi(v0);
        }
        ax *= inv; ay *= inv;
        *(unsigned int*)&agg[((size_t)wid << 7) + lane * 2] =
            (unsigned int)f2b1(ax) | ((unsigned int)f2b1(ay) << 16);
    } else {
        float ax = 0.f, ay = 0.f, az = 0.f, aw = 0.f;
        int i = 0;
        for (; i + 4 <= d; i += 4) {
            int r0 = esrc[s + i + 0], r1 = esrc[s + i + 1];
            int r2 = esrc[s + i + 2], r3 = esrc[s + i + 3];
            uint2 v0 = *(const uint2*)&xsrc[((size_t)r0 << 8) + lane * 4];
            uint2 v1 = *(const uint2*)&xsrc[((size_t)r1 << 8) + lane * 4];
            uint2 v2 = *(const uint2*)&xsrc[((size_t)r2 << 8) + lane * 4];
            uint2 v3 = *(const uint2*)&xsrc[((size_t)r3 << 8) + lane * 4];
            ax += b2f_lo(v0.x); ay += b2f_hi(v0.x);
            az += b2f_lo(v0.y); aw += b2f_hi(v0.y);
            ax += b2f_lo(v1.x); ay += b2f_hi(v1.x);
            az += b2f_lo(v1.y); aw += b2f_hi(v1.y);
            ax += b2f_lo(v2.x); ay += b2f_hi(v2.x);
            az += b2f_lo(v2.y); aw += b2f_hi(v2.y);
            ax += b2f_lo(v3.x); ay += b2f_hi(v3.x);
            az += b2f_lo(v3.y); aw += b2f_hi(v3.y);
        }
        for (; i < d; ++i) {
            int r0 = esrc[s + i];
            uint2 v0 = *(const uint2*)&xsrc[((size_t)r0 << 8) + lane * 4];
            ax += b2f_lo(v0.x); ay += b2f_hi(v0.x);
            az += b2f_lo(v0.y); aw += b2f_hi(v0.y);
        }
        ax *= inv; ay *= inv; az *= inv; aw *= inv;
        uint2 o;
        o.x = (unsigned int)f2b1(ax) | ((unsigned int)f2b1(ay) << 16);
        o.y = (unsigned int)f2b1(az) | ((unsigned int)f2b1(aw) << 16);
        *(uint2*)&agg[((size_t)wid << 8) + lane * 4] = o;
    }
}

// ---------------------------------------------------------------------------
// bf16 MFMA GEMM: h = relu((agg.Wl^T + xdst.Wr^T) * BN_SCALE * g + b), bf16 out
// Block: 512 threads = 8 waves (2 M-halves x 4 N-quarters). Tile 128 x 256.
// ---------------------------------------------------------------------------
template<int KH>
__global__ __launch_bounds__(512) void sage_gemm_mfma(
    const unsigned short* __restrict__ aggb, const unsigned short* __restrict__ xdstb,
    const unsigned short* __restrict__ Wlb, const unsigned short* __restrict__ Wrb,
    const float* __restrict__ g, const float* __restrict__ b,
    unsigned short* __restrict__ h, int n_dst)
{
    __shared__ uint4 A_sh[512];    // [m:128][g':4]
    __shared__ uint4 B_sh[1024];   // [n:256][g':4]

    const int tid  = threadIdx.x;
    const int lane = tid & 63;
    const int wv   = tid >> 6;
    const int mh   = wv >> 2;
    const int n0   = (wv & 3) * 64;
    const int m0g  = blockIdx.x * 128;
    const int lrow = lane & 15;
    const int lgrp = lane >> 4;

    f32x4 acc[4][4];
#pragma unroll
    for (int i = 0; i < 4; ++i)
#pragma unroll
        for (int j = 0; j < 4; ++j)
            acc[i][j] = (f32x4){0.f, 0.f, 0.f, 0.f};

    for (int kp = 0; kp < 2 * KH; kp += 32) {
        const unsigned short* Asrc = (kp < KH) ? aggb : xdstb;
        const unsigned short* Bsrc = (kp < KH) ? Wlb : Wrb;
        const int kbase = (kp < KH) ? kp : kp - KH;

        {
            int m = tid >> 2, gq = tid & 3;
            int r = m0g + m;
            uint4 v = {0, 0, 0, 0};
            if (r < n_dst) v = *(const uint4*)&Asrc[(size_t)r * KH + kbase + gq * 8];
            A_sh[m * 4 + (gq ^ ((m >> 1) & 3))] = v;
        }
        {
            int nb_ = tid >> 2, gq = tid & 3;
#pragma unroll
            for (int i2 = 0; i2 < 2; ++i2) {
                int n = nb_ + 128 * i2;
                uint4 v = *(const uint4*)&Bsrc[(size_t)n * KH + kbase + gq * 8];
                B_sh[n * 4 + (gq ^ ((n >> 1) & 3))] = v;
            }
        }
        __syncthreads();

        short8 av[4], bv[4];
#pragma unroll
        for (int mf = 0; mf < 4; ++mf) {
            int m = mh * 64 + mf * 16 + lrow;
            av[mf] = *reinterpret_cast<const short8*>(&A_sh[m * 4 + (lgrp ^ ((m >> 1) & 3))]);
        }
#pragma unroll
        for (int nf = 0; nf < 4; ++nf) {
            int n = n0 + nf * 16 + lrow;
            bv[nf] = *reinterpret_cast<const short8*>(&B_sh[n * 4 + (lgrp ^ ((n >> 1) & 3))]);
        }
#pragma unroll
        for (int mf = 0; mf < 4; ++mf)
#pragma unroll
            for (int nf = 0; nf < 4; ++nf)
                acc[mf][nf] = __builtin_amdgcn_mfma_f32_16x16x32_bf16(
                    av[mf], bv[nf], acc[mf][nf], 0, 0, 0);
        __syncthreads();
    }

    // epilogue: BN + ReLU, bf16 store. C/D: col=lane&15, row=(lane>>4)*4+reg.
#pragma unroll
    for (int nf = 0; nf < 4; ++nf) {
        int n = n0 + nf * 16 + lrow;
        float sc = g[n] * BN_SCALE;
        float bi = b[n];
#pragma unroll
        for (int mf = 0; mf < 4; ++mf) {
            int mbase = m0g + mh * 64 + mf * 16 + lgrp * 4;
#pragma unroll
            for (int r = 0; r < 4; ++r) {
                int m = mbase + r;
                if (m < n_dst) {
                    float vv = fmaxf(acc[mf][nf][r] * sc + bi, 0.f);
                    h[(size_t)m * HID + n] = f2b1(vv);
                }
            }
        }
    }
}

// ---------------------------------------------------------------------------
// Final layer via MFMA: z = [h0|h1|h2][:25000] @ WlinPad.T + blin (N padded
// to 64, rows 47..63 zero), fused log_softmax, fp32 out.
// Block: 256 threads = 4 waves. Tile 128 rows x 64 cols. K = 768 (three
// 256-aligned segments from h0/h1/h2). Per wave: 2x4 frags of 16x16.
// ---------------------------------------------------------------------------
__global__ __launch_bounds__(256) void final_mfma(
    const unsigned short* __restrict__ h0, const unsigned short* __restrict__ h1,
    const unsigned short* __restrict__ h2, const unsigned short* __restrict__ wlinb,
    const float* __restrict__ blin, float* __restrict__ out)
{
    __shared__ uint4 A_sh[512];   // [m:128][g':4]
    __shared__ uint4 B_sh[256];   // [n:64][g':4]

    const int tid  = threadIdx.x;
    const int lane = tid & 63;
    const int wv   = tid >> 6;          // 0..3 -> 32-row band
    const int m0g  = blockIdx.x * 128;
    const int lrow = lane & 15;
    const int lgrp = lane >> 4;

    f32x4 acc[2][4];
#pragma unroll
    for (int i = 0; i < 2; ++i)
#pragma unroll
        for (int j = 0; j < 4; ++j)
            acc[i][j] = (f32x4){0.f, 0.f, 0.f, 0.f};

    for (int kp = 0; kp < 768; kp += 32) {
        const int seg = kp >> 8;
        const unsigned short* hs = (seg == 0) ? h0 : (seg == 1) ? h1 : h2;
        const int kseg = kp & 255;

        // stage A: 128 rows x 32 k (2 x 16B per thread)
#pragma unroll
        for (int l = 0; l < 2; ++l) {
            int idx = tid + l * 256;
            int m = idx >> 2, gq = idx & 3;
            int r = m0g + m;
            uint4 v = {0, 0, 0, 0};
            if (r < ENDR) v = *(const uint4*)&hs[(size_t)r * HID + kseg + gq * 8];
            A_sh[m * 4 + (gq ^ ((m >> 1) & 3))] = v;
        }
        // stage B: 64 rows x 32 k (1 x 16B per thread)
        {
            int n = tid >> 2, gq = tid & 3;
            uint4 v = *(const uint4*)&wlinb[(size_t)n * 768 + kp + gq * 8];
            B_sh[n * 4 + (gq ^ ((n >> 1) & 3))] = v;
        }
        __syncthreads();

        short8 av[2], bv[4];
#pragma unroll
        for (int mf = 0; mf < 2; ++mf) {
            int m = wv * 32 + mf * 16 + lrow;
            av[mf] = *reinterpret_cast<const short8*>(&A_sh[m * 4 + (lgrp ^ ((m >> 1) & 3))]);
        }
#pragma unroll
        for (int nf = 0; nf < 4; ++nf) {
            int n = nf * 16 + lrow;
            bv[nf] = *reinterpret_cast<const short8*>(&B_sh[n * 4 + (lgrp ^ ((n >> 1) & 3))]);
        }
#pragma unroll
        for (int mf = 0; mf < 2; ++mf)
#pragma unroll
            for (int nf = 0; nf < 4; ++nf)
                acc[mf][nf] = __builtin_amdgcn_mfma_f32_16x16x32_bf16(
                    av[mf], bv[nf], acc[mf][nf], 0, 0, 0);
        __syncthreads();
    }

    // epilogue: z = acc + blin (cols >= OUTC masked), log_softmax over the
    // row's 64 cols = 4 nf-frags x 16 lanes of this lane's 16-lane group.
    float bl = (lrow < OUTC - 32) ? 0.f : 0.f;  // placeholder (blin read below)
    float bv4[4];
#pragma unroll
    for (int nf = 0; nf < 4; ++nf) {
        int n = nf * 16 + lrow;
        bv4[nf] = (n < OUTC) ? blin[n] : 0.f;
    }

#pragma unroll
    for (int mf = 0; mf < 2; ++mf) {
        float z[4][4];   // [reg(row)][nf]
        float rmax[4], rsum[4];
#pragma unroll
        for (int r = 0; r < 4; ++r) {
            float mx = -INFINITY;
#pragma unroll
            for (int nf = 0; nf < 4; ++nf) {
                int n = nf * 16 + lrow;
                float v = (n < OUTC) ? acc[mf][nf][r] + bv4[nf] : -INFINITY;
                z[r][nf] = v;
                mx = fmaxf(mx, v);
            }
            rmax[r] = mx;
        }
        // reduce max across the 16-lane group (lane bits 0..3)
#pragma unroll
        for (int off = 8; off >= 1; off >>= 1)
#pragma unroll
            for (int r = 0; r < 4; ++r)
                rmax[r] = fmaxf(rmax[r], __shfl_xor(rmax[r], off));
#pragma unroll
        for (int r = 0; r < 4; ++r) {
            float s = 0.f;
#pragma unroll
            for (int nf = 0; nf < 4; ++nf)
                s += (z[r][nf] > -INFINITY) ? expf(z[r][nf] - rmax[r]) : 0.f;
            rsum[r] = s;
        }
#pragma unroll
        for (int off = 8; off >= 1; off >>= 1)
#pragma unroll
            for (int r = 0; r < 4; ++r)
                rsum[r] += __shfl_xor(rsum[r], off);

#pragma unroll
        for (int r = 0; r < 4; ++r) {
            int m = m0g + wv * 32 + mf * 16 + lgrp * 4 + r;
            if (m < ENDR) {
                float lg = rmax[r] + logf(rsum[r]);
#pragma unroll
                for (int nf = 0; nf < 4; ++nf) {
                    int n = nf * 16 + lrow;
                    if (n < OUTC) out[(size_t)m * OUTC + n] = z[r][nf] - lg;
                }
            }
        }
    }
    (void)bl;
}

// ---------------------------------------------------------------------------
extern "C" void kernel_launch(void* const* d_in, const int* in_sizes, int n_in,
                              void* d_out, int out_size, void* d_ws, size_t ws_size,
                              hipStream_t stream)
{
    const float* x    = (const float*)d_in[0];
    const int* rows[3] = {(const int*)d_in[1], (const int*)d_in[3], (const int*)d_in[5]};
    const int* cols[3] = {(const int*)d_in[2], (const int*)d_in[4], (const int*)d_in[6]};
    const float* Wl[3] = {(const float*)d_in[7],  (const float*)d_in[11], (const float*)d_in[15]};
    const float* Wr[3] = {(const float*)d_in[8],  (const float*)d_in[12], (const float*)d_in[16]};
    const float* gs[3] = {(const float*)d_in[9],  (const float*)d_in[13], (const float*)d_in[17]};
    const float* bs[3] = {(const float*)d_in[10], (const float*)d_in[14], (const float*)d_in[18]};
    const float* Wlin = (const float*)d_in[19];
    const float* blin = (const float*)d_in[20];
    float* out = (float*)d_out;

    const int Es[3]   = {in_sizes[1], in_sizes[3], in_sizes[5]};
    const int ndst[3] = {N_DST0, N_DST1, N_DST2};
    const int Ks[3]   = {128, 256, 256};

    // ----- workspace layout (bytes) -----
    // xb    @ 0          : 51,200,000
    // h0b   @ 51200000   : 51,200,000
    // h1b   @ 102400000  : 25,600,000
    // h2b   @ 128000000  : 12,800,000
    // aggb  @ 140800000  : 25,600,000  (ends 166,400,000)
    // wb    @ 166400000  : 655,360     (ends 167,055,360)
    // wlinb @ 167100032  : 98,304      (ends 167,198,336; 64x768 bf16 padded)
    // ints  @ 167600000  : esrc 1.6M | deg/excl/cursor 100k | blkoff
    char* base = (char*)d_ws;
    unsigned short* xb   = (unsigned short*)(base);
    unsigned short* h0b  = (unsigned short*)(base + 51200000);
    unsigned short* h1b  = (unsigned short*)(base + 102400000);
    unsigned short* h2b  = (unsigned short*)(base + 128000000);
    unsigned short* aggb = (unsigned short*)(base + 140800000);
    unsigned short* wb   = (unsigned short*)(base + 166400000);
    unsigned short* wlinb= (unsigned short*)(base + 167100032);
    int* ibase  = (int*)(base + 167600000);
    int* esrc   = ibase;
    int* deg    = ibase + 1600000;
    int* excl   = ibase + 1700000;
    int* cursor = ibase + 1800000;
    int* blkoff = ibase + 1900000;

    unsigned short* Wlb[3] = {wb,          wb + 65536,  wb + 196608};
    unsigned short* Wrb[3] = {wb + 32768,  wb + 131072, wb + 262144};
    const int wsz[3] = {256 * 128, 256 * 256, 256 * 256};

    // ----- convert x and weights to bf16; build padded bf16 Wlin -----
    f2b_kernel<<<(25600000 / 4 + 255) / 256, 256, 0, stream>>>(x, xb, 25600000);
    for (int L = 0; L < 3; ++L) {
        f2b_kernel<<<(wsz[L] / 4 + 255) / 256, 256, 0, stream>>>(Wl[L], Wlb[L], wsz[L]);
        f2b_kernel<<<(wsz[L] / 4 + 255) / 256, 256, 0, stream>>>(Wr[L], Wrb[L], wsz[L]);
    }
    hipMemsetAsync(wlinb, 0, 64 * 768 * sizeof(unsigned short), stream);
    f2b_kernel<<<((OUTC * 768) / 4 + 255) / 256, 256, 0, stream>>>(
        Wlin, wlinb, OUTC * 768);

    const unsigned short* hsrc[3] = {xb, h0b, h1b};
    unsigned short* hdst[3] = {h0b, h1b, h2b};

    for (int L = 0; L < 3; ++L) {
        const int E = Es[L], nd = ndst[L];
        const int nb = (nd + 1023) / 1024;
        hipMemsetAsync(deg, 0, (size_t)nd * sizeof(int), stream);
        deg_count<<<(E + 255) / 256, 256, 0, stream>>>(cols[L], deg, E);
        scan_local<<<nb, 256, 0, stream>>>(deg, excl, blkoff, nd);
        scan_blksum<<<1, 256, 0, stream>>>(blkoff, nb);
        add_offsets<<<(nd + 255) / 256, 256, 0, stream>>>(excl, blkoff, cursor, nd);
        csr_fill<<<(E + 255) / 256, 256, 0, stream>>>(rows[L], cols[L], cursor, esrc, E);

        if (Ks[L] == 128) {
            gather_mean<7><<<(nd + 3) / 4, 256, 0, stream>>>(hsrc[L], esrc, excl, deg, aggb, nd);
            sage_gemm_mfma<128><<<(nd + 127) / 128, 512, 0, stream>>>(
                aggb, hsrc[L], Wlb[L], Wrb[L], gs[L], bs[L], hdst[L], nd);
        } else {
            gather_mean<8><<<(nd + 3) / 4, 256, 0, stream>>>(hsrc[L], esrc, excl, deg, aggb, nd);
            sage_gemm_mfma<256><<<(nd + 127) / 128, 512, 0, stream>>>(
                aggb, hsrc[L], Wlb[L], Wrb[L], gs[L], bs[L], hdst[L], nd);
        }
    }

    final_mfma<<<(ENDR + 127) / 128, 256, 0, stream>>>(
        h0b, h1b, h2b, wlinb, blin, out);
}